// Round 3
// baseline (157.478 us; speedup 1.0000x reference)
//
#include <hip/hip_runtime.h>

typedef __attribute__((ext_vector_type(8))) __bf16 bf16x8;
typedef __attribute__((ext_vector_type(4))) __bf16 bf16x4;
typedef __attribute__((ext_vector_type(4))) float f32x4;

#define B_ 16
#define S_ 1024
#define D_ 1024
#define R_ 128

// proj [D][R] fp32  ->  projT [R][D] bf16  (transpose + cast, LDS tiled)
__global__ __launch_bounds__(256) void k_transpose(const float* __restrict__ proj,
                                                   __bf16* __restrict__ projT) {
    __shared__ __bf16 tile[64][66];
    const int k0 = blockIdx.x * 64;
    const int r0 = blockIdx.y * 64;
#pragma unroll
    for (int it = 0; it < 16; ++it) {
        int idx = it * 256 + threadIdx.x;
        int kk = idx >> 6, rr = idx & 63;
        tile[kk][rr] = (__bf16)proj[(size_t)(k0 + kk) * R_ + (r0 + rr)];
    }
    __syncthreads();
#pragma unroll
    for (int it = 0; it < 16; ++it) {
        int idx = it * 256 + threadIdx.x;
        int rr = idx >> 6, kk = idx & 63;
        projT[(size_t)(r0 + rr) * D_ + (k0 + kk)] = tile[kk][rr];
    }
}

// t = batch @ proj (bf16 MFMA) + bf16 t + sq_norms.
// v3: A staged through LDS with fully-coalesced 1KB loads (1 row/instr),
// fragments fed by ds_read_b128 (row stride 528 B -> 2-way aliasing = free).
// Stage LDS unioned with the K-reduction buffer: 33 KB -> 4 blocks/CU.
#define STG_LD 264  // 256 + 8 elems pad (528 B rows)
__global__ __launch_bounds__(256, 4) void k_proj(const float* __restrict__ batch,
                                                 const __bf16* __restrict__ projT,
                                                 __bf16* __restrict__ t,
                                                 float* __restrict__ sqn) {
    const int wave = threadIdx.x >> 6;
    const int lane = threadIdx.x & 63;
    const int ln = lane & 15;   // A-row / D-col selector
    const int q  = lane >> 4;   // quad: k-chunk (input), row-group (output)
    const int m0 = blockIdx.x * 16;
    const int kbase = wave * 256;   // this wave's K slice

    __shared__ __align__(16) char smraw[4 * 16 * STG_LD * 2];  // 33792 B
    __bf16 (*stg)[STG_LD] =
        reinterpret_cast<__bf16(*)[STG_LD]>(smraw + wave * (16 * STG_LD * 2));

    // ---- stage this wave's 16 rows x 256 k fp32 -> bf16 LDS ----
    const float* abase = batch + (size_t)m0 * D_ + kbase;
#pragma unroll
    for (int r = 0; r < 16; ++r) {
        float4 v = *(const float4*)(abase + (size_t)r * D_ + lane * 4);
        bf16x4 h = {(__bf16)v.x, (__bf16)v.y, (__bf16)v.z, (__bf16)v.w};
        *(bf16x4*)&stg[r][lane * 4] = h;
    }

    f32x4 acc[8];
#pragma unroll
    for (int ni = 0; ni < 8; ++ni) acc[ni] = f32x4{0.f, 0.f, 0.f, 0.f};

#pragma unroll
    for (int k0 = 0; k0 < 256; k0 += 32) {
        const int ka = k0 + q * 8;
        bf16x8 af = *(const bf16x8*)&stg[ln][ka];  // A[m=ln][k=ka..ka+7]
#pragma unroll
        for (int ni = 0; ni < 8; ++ni) {
            // B[k][n] = projT[n][k], contiguous 16 B (L2-resident)
            bf16x8 bf = *(const bf16x8*)(projT + (size_t)(ni * 16 + ln) * D_ + kbase + ka);
            acc[ni] = __builtin_amdgcn_mfma_f32_16x16x32_bf16(af, bf, acc[ni], 0, 0, 0);
        }
    }

    // ---- cross-wave K reduction (LDS reused: barrier first) ----
    __syncthreads();
    f32x4 (*red)[64] = reinterpret_cast<f32x4(*)[64]>(smraw);          // [4][8][64] -> [w*8+ni][lane]
    float (*sqpart)[16] = reinterpret_cast<float(*)[16]>(smraw + 32768);
#pragma unroll
    for (int ni = 0; ni < 8; ++ni) red[wave * 8 + ni][lane] = acc[ni];
    __syncthreads();

    float sq[4] = {0.f, 0.f, 0.f, 0.f};
#pragma unroll
    for (int p = 0; p < 2; ++p) {
        const int ni = wave * 2 + p;
        f32x4 v = red[ni][lane];
#pragma unroll
        for (int w = 1; w < 4; ++w) {
            f32x4 u = red[w * 8 + ni][lane];
            v[0] += u[0]; v[1] += u[1]; v[2] += u[2]; v[3] += u[3];
        }
        // D mapping: col = ni*16 + ln, row = q*4 + r
#pragma unroll
        for (int r = 0; r < 4; ++r) {
            __bf16 h = (__bf16)v[r];
            t[(size_t)(m0 + q * 4 + r) * R_ + ni * 16 + ln] = h;
            float f = (float)h;
            sq[r] += f * f;  // from *rounded* t: keeps diagonal consistent
        }
    }
#pragma unroll
    for (int r = 0; r < 4; ++r) {
#pragma unroll
        for (int off = 1; off < 16; off <<= 1)
            sq[r] += __shfl_xor(sq[r], off, 64);
    }
    if (ln == 0) {
#pragma unroll
        for (int r = 0; r < 4; ++r) sqpart[wave][q * 4 + r] = sq[r];
    }
    __syncthreads();
    if (threadIdx.x < 16) {
        float s = sqpart[0][threadIdx.x] + sqpart[1][threadIdx.x] +
                  sqpart[2][threadIdx.x] + sqpart[3][threadIdx.x];
        sqn[m0 + threadIdx.x] = s;
    }
}

// Per batch: cross = t @ t^T; out = max(0, sqn_i + sqn_j - 2*cross).
// v2: stores TRANSPOSED (d is symmetric) so each lane's 4 acc elements
// (4 consecutive rows, one col) become one float4 store -> 4x fewer stores.
__global__ __launch_bounds__(256, 4) void k_gram(const __bf16* __restrict__ t,
                                                 const float* __restrict__ sqn,
                                                 float* __restrict__ out) {
    const int b = blockIdx.z;
    const int wave = threadIdx.x >> 6;
    const int lane = threadIdx.x & 63;
    const int ln = lane & 15;
    const int q  = lane >> 4;
    const int wi = wave >> 1, wj = wave & 1;
    const int i0 = blockIdx.y * 128 + wi * 64;
    const int j0 = blockIdx.x * 128 + wj * 64;
    const __bf16* tb = t + (size_t)b * S_ * R_;
    const float* sqb = sqn + (size_t)b * S_;

    f32x4 acc[4][4];
#pragma unroll
    for (int mi = 0; mi < 4; ++mi)
#pragma unroll
        for (int ni = 0; ni < 4; ++ni) acc[mi][ni] = f32x4{0.f, 0.f, 0.f, 0.f};

#pragma unroll
    for (int k0 = 0; k0 < R_; k0 += 32) {
        const int ka = k0 + q * 8;
        bf16x8 af[4], bfm[4];
#pragma unroll
        for (int mi = 0; mi < 4; ++mi)
            af[mi] = *(const bf16x8*)(tb + (size_t)(i0 + mi * 16 + ln) * R_ + ka);
#pragma unroll
        for (int ni = 0; ni < 4; ++ni)
            bfm[ni] = *(const bf16x8*)(tb + (size_t)(j0 + ni * 16 + ln) * R_ + ka);
#pragma unroll
        for (int mi = 0; mi < 4; ++mi)
#pragma unroll
            for (int ni = 0; ni < 4; ++ni)
                acc[mi][ni] = __builtin_amdgcn_mfma_f32_16x16x32_bf16(
                    af[mi], bfm[ni], acc[mi][ni], 0, 0, 0);
    }

    float sqj[4];
#pragma unroll
    for (int ni = 0; ni < 4; ++ni) sqj[ni] = sqb[j0 + ni * 16 + ln];

    float* outb = out + (size_t)b * S_ * S_;
#pragma unroll
    for (int mi = 0; mi < 4; ++mi) {
        // sqn for the 4 consecutive rows this lane's acc covers
        float4 si4 = *(const float4*)(sqb + i0 + mi * 16 + q * 4);
#pragma unroll
        for (int ni = 0; ni < 4; ++ni) {
            const int j = j0 + ni * 16 + ln;
            float4 o;
            o.x = fmaxf(si4.x + sqj[ni] - 2.f * acc[mi][ni][0], 0.f);
            o.y = fmaxf(si4.y + sqj[ni] - 2.f * acc[mi][ni][1], 0.f);
            o.z = fmaxf(si4.z + sqj[ni] - 2.f * acc[mi][ni][2], 0.f);
            o.w = fmaxf(si4.w + sqj[ni] - 2.f * acc[mi][ni][3], 0.f);
            // symmetric: out[j][i..i+3] = d[i..i+3][j]
            *(float4*)(outb + (size_t)j * S_ + i0 + mi * 16 + q * 4) = o;
        }
    }
}

extern "C" void kernel_launch(void* const* d_in, const int* in_sizes, int n_in,
                              void* d_out, int out_size, void* d_ws, size_t ws_size,
                              hipStream_t stream) {
    const float* batch = (const float*)d_in[0];  // [16,1024,1024] fp32
    const float* proj  = (const float*)d_in[1];  // [1024,128] fp32
    float* out = (float*)d_out;                  // [16,1024,1024] fp32

    char* ws = (char*)d_ws;
    __bf16* t     = (__bf16*)ws;                                   // 4 MB
    __bf16* projT = (__bf16*)(ws + (size_t)B_ * S_ * R_ * 2);      // 256 KB
    float*  sqn   = (float*)(ws + (size_t)B_ * S_ * R_ * 2
                                + (size_t)R_ * D_ * 2);            // 64 KB

    k_transpose<<<dim3(D_ / 64, R_ / 64), 256, 0, stream>>>(proj, projT);
    k_proj<<<dim3((B_ * S_) / 16), 256, 0, stream>>>(batch, projT, t, sqn);
    k_gram<<<dim3(S_ / 128, S_ / 128, B_), 256, 0, stream>>>(t, sqn, out);
}